// Round 16
// baseline (70.902 us; speedup 1.0000x reference)
//
#include <hip/hip_runtime.h>

// CTC batch cost (keras ctc_batch_cost semantics), blank = C-1.
// 256 blocks x 128 threads: wave 0 = DP consumer, wave 1 = producer.
// Lane L owns states 4L..4L+3; lane 63 also owns state 256.
// NEW: f32 probability-domain DP with PER-LANE power-of-2 scale tracking
// (r2's f32 failure was WAVE-GLOBAL scaling -- the ~165-nat across-state
// spread broke it; per-lane localizes range to 4 adjacent states).
// - cross-lane pa3 rebased by exact v_ldexp_f32 with dl = sh[L-1]-sh[L]
// - rescale every CK=8 steps: per-lane exponent extract (exact pow-2),
//   empty lanes adopt the LAST OCCUPIED lane's shift (occupied lanes are
//   a prefix: mass flows only toward higher s) via ballot+readlane
// - frontier jump guard: dl>96 -> zero lane content (<=2^-96 relative to
//   incoming) and adopt left shift; dl clamped to 96 -> no f32 overflow
// Producer identical to proven r11/r15: 17 global_load_lds per chunk into
// a 4-slot f32 LDS ring, depth-2 (34 outstanding), counted vmcnt(17).

constexpr int   Tn    = 1024;
constexpr int   Cc    = 128;
constexpr int   Ln    = 128;
constexpr float EPSf  = 1e-7f;
constexpr int   CK    = 8;     // rows per chunk == rescale period
constexpr int   NSLOT = 4;     // LDS ring slots

__device__ __forceinline__ float dpp_shr1_f32(float x) {   // lane L <- lane L-1; lane0 -> 0
    int s = __builtin_amdgcn_update_dpp(0, __float_as_int(x), 0x138, 0xf, 0xf, true);
    return __int_as_float(s);
}
__device__ __forceinline__ int dpp_shr1_i32(int x) {       // lane L <- lane L-1; lane0 -> 0
    return __builtin_amdgcn_update_dpp(0, x, 0x138, 0xf, 0xf, true);
}

__global__ __launch_bounds__(128, 1)
void ctc_fwd_kernel(const int*   __restrict__ y_true,
                    const float* __restrict__ y_pred,
                    const int*   __restrict__ in_len,
                    const int*   __restrict__ lab_len,
                    float*       __restrict__ out)
{
    const int tid = threadIdx.x;
    const int L   = tid & 63;
    const int b   = blockIdx.x;
    const int il  = in_len[b];
    const int ll  = lab_len[b];
    const int blank = Cc - 1;

    const int* yb   = y_true + (size_t)b * Ln;
    const int  lab1 = yb[2 * L];
    const int  lab2 = yb[2 * L + 1];

    const float* base = y_pred + (size_t)b * Tn * Cc;
    const int steps = (il > 0) ? (il - 1) : 0;
    const int nfull = steps / CK;
    const int nch   = (steps + CK - 1) / CK;

    __shared__ float f32L1[NSLOT][CK][64];
    __shared__ float f32L2[NSLOT][CK][64];
    __shared__ float f32BK[NSLOT][CK];
    __shared__ float sAf[258];
    __shared__ int   sShL[64];

#define BARRIER() do {                                                  \
    __builtin_amdgcn_sched_barrier(0);                                  \
    asm volatile("" ::: "memory");                                      \
    __builtin_amdgcn_s_barrier();                                       \
    asm volatile("" ::: "memory");                                      \
    __builtin_amdgcn_sched_barrier(0);                                  \
} while (0)

#define WAIT_VM(n) do {                                                 \
    __builtin_amdgcn_sched_barrier(0);                                  \
    asm volatile("s_waitcnt vmcnt(" #n ")");                            \
    __builtin_amdgcn_sched_barrier(0);                                  \
} while (0)

    if (tid >= 64) {
        // ---------------- producer wave (r11-proven) ----------------
#define ISSUE_CHUNK(k) do {                                             \
    const int slot_ = (k) & (NSLOT - 1);                                \
    {                                                                   \
        int tb_ = 1 + (k) * CK + L; if (tb_ > steps) tb_ = steps; if (tb_ < 0) tb_ = 0; \
        const float* g_ = base + (size_t)tb_ * Cc + blank;              \
        if (L < CK)                                                     \
            __builtin_amdgcn_global_load_lds(                           \
                (const __attribute__((address_space(1))) void*)g_,      \
                (__attribute__((address_space(3))) void*)&f32BK[slot_][0], 4, 0, 0); \
    }                                                                   \
    _Pragma("unroll")                                                   \
    for (int r_ = 0; r_ < CK; ++r_) {                                   \
        int t_ = 1 + (k) * CK + r_; if (t_ > steps) t_ = steps; if (t_ < 0) t_ = 0; \
        const float* row_ = base + (size_t)t_ * Cc;                     \
        __builtin_amdgcn_global_load_lds(                               \
            (const __attribute__((address_space(1))) void*)(row_ + lab1), \
            (__attribute__((address_space(3))) void*)&f32L1[slot_][r_][0], 4, 0, 0); \
        __builtin_amdgcn_global_load_lds(                               \
            (const __attribute__((address_space(1))) void*)(row_ + lab2), \
            (__attribute__((address_space(3))) void*)&f32L2[slot_][r_][0], 4, 0, 0); \
    }                                                                   \
} while (0)

        ISSUE_CHUNK(0);
        ISSUE_CHUNK(1);              // 34 outstanding
        WAIT_VM(17);                 // chunk 0 landed
        BARRIER();
        for (int i = 0; i < nch; ++i) {
            if (i + 2 < nch) {
                ISSUE_CHUNK(i + 2);
                WAIT_VM(17);
            } else {
                WAIT_VM(0);
            }
            BARRIER();
        }
        return;
#undef ISSUE_CHUNK
    }

    // ---------------- consumer wave (f32 per-lane-scale DP) ----------------
    const int  labp  = (L > 0) ? yb[2 * L - 1] : -1;
    const float skm1 = ((L > 0) && (lab1 != blank) && (lab1 != labp)) ? 1.0f : 0.0f;
    const float skm3 = ((lab2 != blank) && (lab2 != lab1)) ? 1.0f : 0.0f;

    float a0 = 0.f, a1v = 0.f, a2v = 0.f, a3v = 0.f, a4v = 0.f;
    if (L == 0) {
        a0  = base[blank] + EPSf;
        a1v = (ll > 0) ? (base[lab1] + EPSf) : 0.f;
    }
    int sh = 0;      // per-lane power-of-2 shift (alpha_true = a * 2^sh)
    int dl = 0;      // sh[L-1] - sh[L], clamped; fixed within a chunk

#define DPSTEP(qb_, q1_, q2_) do {                                      \
    const float pa3_ = ldexpf(dpp_shr1_f32(a3v), dl);                   \
    const float n0_ = (a0 + pa3_) * (qb_);                              \
    const float n1_ = fmaf(skm1, pa3_, a0 + a1v) * (q1_);               \
    const float n2_ = (a2v + a1v) * (qb_);                              \
    const float n3_ = fmaf(skm3, a1v, a3v + a2v) * (q2_);               \
    const float n4_ = (a4v + a3v) * (qb_);                              \
    a0 = n0_; a1v = n1_; a2v = n2_; a3v = n3_; a4v = n4_;               \
} while (0)

#define RESCALE() do {                                                  \
    float m_ = fmaxf(fmaxf(fmaxf(a0, a1v), fmaxf(a2v, a3v)), a4v);      \
    const bool occ_ = (m_ > 0.f);                                       \
    const int  ef_  = (int)((__float_as_uint(m_) >> 23) & 255u);        \
    const int  eff_ = occ_ ? ef_ : 127;                                 \
    const int  e_   = eff_ - 127;                                       \
    const float sc_ = __uint_as_float((unsigned)(254 - eff_) << 23);    \
    a0 *= sc_; a1v *= sc_; a2v *= sc_; a3v *= sc_; a4v *= sc_;          \
    const int nsh_ = sh + e_;                                           \
    const unsigned long long mk_ = __ballot(occ_);                      \
    const int last_ = mk_ ? (63 - __builtin_clzll(mk_)) : 0;            \
    const int adopt_ = __builtin_amdgcn_readlane(nsh_, last_);          \
    sh = occ_ ? nsh_ : adopt_;                                          \
    bool zf_ = false;                                                   \
    _Pragma("unroll")                                                   \
    for (int k_ = 0; k_ < 3; ++k_) {                                    \
        const int shl_ = dpp_shr1_i32(sh);                              \
        const int d_   = (L == 0) ? 0 : (shl_ - sh);                    \
        const bool big_ = (L > 0) && (d_ > 96);                         \
        sh = big_ ? shl_ : sh;                                          \
        zf_ = zf_ || big_;                                              \
    }                                                                   \
    {                                                                   \
        const int shl_ = dpp_shr1_i32(sh);                              \
        int d_ = (L == 0) ? 0 : (shl_ - sh);                            \
        dl = (d_ > 96) ? 96 : d_;                                       \
    }                                                                   \
    if (zf_) { a0 = 0.f; a1v = 0.f; a2v = 0.f; a3v = 0.f; a4v = 0.f; }  \
} while (0)

    BARRIER();                       // prologue: chunk 0 ready

    for (int i = 0; i < nch; ++i) {
        const int slot = i & (NSLOT - 1);

        // Batch-read chunk i (+eps) into registers before the barrier.
        float qb[CK], q1[CK], q2[CK];
#pragma unroll
        for (int r = 0; r < CK; ++r) {
            qb[r] = f32BK[slot][r]    + EPSf;
            q1[r] = f32L1[slot][r][L] + EPSf;
            q2[r] = f32L2[slot][r][L] + EPSf;
        }

        BARRIER();                   // chunk i+1 ready

        if (i < nfull) {
#pragma unroll
            for (int r = 0; r < CK; ++r)
                DPSTEP(qb[r], q1[r], q2[r]);
        } else {
#pragma unroll
            for (int r = 0; r < CK; ++r) {
                if (1 + i * CK + r <= steps)
                    DPSTEP(qb[r], q1[r], q2[r]);
            }
        }
        RESCALE();                   // every 8 steps (exact pow-2 bookkeeping)
    }

    // ---- readout: loglik(log2) = sh + log2(a); combine two states ----
    sAf[4 * L + 0] = a0;
    sAf[4 * L + 1] = a1v;
    sAf[4 * L + 2] = a2v;
    sAf[4 * L + 3] = a3v;
    if (L == 63) sAf[256] = a4v;
    sShL[L] = sh;

    if (L == 0) {
        const int end = 2 * ll;
        int pi = end - 1; if (pi < 0) pi = 0;
        const float ve = sAf[end];
        float vp = sAf[pi];
        if (ll <= 0) vp = 0.f;
        int ie = end >> 2; if (ie > 63) ie = 63;
        int ip = pi  >> 2; if (ip > 63) ip = 63;
        const int she = sShL[ie];
        const int shp = sShL[ip];
        const float le = (ve > 0.f) ? ((float)she + log2f(ve)) : -3.0e38f;
        const float lp = (vp > 0.f) ? ((float)shp + log2f(vp)) : -3.0e38f;
        const float mx = fmaxf(le, lp);
        const float r  = mx + log2f(exp2f(le - mx) + exp2f(lp - mx));
        out[b] = -0.69314718055994530942f * r;
    }

#undef BARRIER
#undef WAIT_VM
#undef DPSTEP
#undef RESCALE
}

extern "C" void kernel_launch(void* const* d_in, const int* in_sizes, int n_in,
                              void* d_out, int out_size, void* d_ws, size_t ws_size,
                              hipStream_t stream) {
    const int*   y_true  = (const int*)  d_in[0];
    const float* y_pred  = (const float*)d_in[1];
    const int*   in_len  = (const int*)  d_in[2];
    const int*   lab_len = (const int*)  d_in[3];
    float*       out     = (float*)      d_out;

    ctc_fwd_kernel<<<dim3(256), dim3(128), 0, stream>>>(y_true, y_pred, in_len, lab_len, out);
}

// Round 17
// 55.966 us; speedup vs baseline: 1.2669x; 1.2669x over previous
//
#include <hip/hip_runtime.h>

// CTC batch cost (keras ctc_batch_cost semantics), blank = C-1.
// 256 blocks x 128 threads: wave 0 = DP consumer, wave 1 = producer.
// Lane L owns states 4L..4L+3; lane 63 also owns state 256.
// f64 probability-domain DP (no transcendentals in the loop), exact
// power-of-2 rescale every 2 chunks (24 steps) via int-domain exponent
// max (hi-word v_max_i32 chain + DPP reduce -- alphas are >=0 so int
// ordering == IEEE ordering). Blank column read as 3x ds_read_b128
// broadcast (12 floats, 16B-aligned rows). Producer: 25 global_load_lds
// per chunk into a 4-slot f32 LDS ring, depth-2 (50 outstanding),
// counted s_waitcnt vmcnt(25) + raw s_barrier (r13-proven skeleton).
// r16's f32 per-lane-scale DP REVERTED (58->71us: ldexp + serial
// rescale fix-up chain outweighed the saved cvts).

constexpr int   Tn    = 1024;
constexpr int   Cc    = 128;
constexpr int   Ln    = 128;
constexpr float EPSf  = 1e-7f;
constexpr int   CK    = 12;    // rows per chunk; rescale every 2 chunks
constexpr int   NSLOT = 4;     // LDS ring slots

__device__ __forceinline__ int dpp_max_i32(int m) {
    int o;
    o = __builtin_amdgcn_update_dpp(0, m, 0x111, 0xf, 0xf, false); m = o > m ? o : m; // row_shr:1
    o = __builtin_amdgcn_update_dpp(0, m, 0x112, 0xf, 0xf, false); m = o > m ? o : m; // row_shr:2
    o = __builtin_amdgcn_update_dpp(0, m, 0x114, 0xf, 0xf, false); m = o > m ? o : m; // row_shr:4
    o = __builtin_amdgcn_update_dpp(0, m, 0x118, 0xf, 0xf, false); m = o > m ? o : m; // row_shr:8
    o = __builtin_amdgcn_update_dpp(0, m, 0x142, 0xf, 0xf, false); m = o > m ? o : m; // row_bcast:15
    o = __builtin_amdgcn_update_dpp(0, m, 0x143, 0xf, 0xf, false); m = o > m ? o : m; // row_bcast:31
    return m;   // lane 63 holds the wave max
}

// lane L gets lane L-1's value; lane 0 gets exact +0.0 (bound_ctrl=1).
__device__ __forceinline__ double dpp_shr1_f64(double x) {
    const int lo = __double2loint(x), hi = __double2hiint(x);
    const int slo = __builtin_amdgcn_update_dpp(0, lo, 0x138, 0xf, 0xf, true); // wave_shr:1
    const int shi = __builtin_amdgcn_update_dpp(0, hi, 0x138, 0xf, 0xf, true);
    return __hiloint2double(shi, slo);
}

__global__ __launch_bounds__(128, 1)
void ctc_fwd_kernel(const int*   __restrict__ y_true,
                    const float* __restrict__ y_pred,
                    const int*   __restrict__ in_len,
                    const int*   __restrict__ lab_len,
                    float*       __restrict__ out)
{
    const int tid = threadIdx.x;
    const int L   = tid & 63;            // lane within wave
    const int b   = blockIdx.x;
    const int il  = in_len[b];
    const int ll  = lab_len[b];
    const int blank = Cc - 1;

    const int* yb   = y_true + (size_t)b * Ln;
    const int  lab1 = yb[2 * L];                       // label for state 4L+1
    const int  lab2 = yb[2 * L + 1];                   // label for state 4L+3

    const float* base = y_pred + (size_t)b * Tn * Cc;
    const int steps = (il > 0) ? (il - 1) : 0;         // updates run t = 1 .. il-1
    const int nfull = steps / CK;
    const int nch   = (steps + CK - 1) / CK;

    __shared__ float f32L1[NSLOT][CK][64];
    __shared__ float f32L2[NSLOT][CK][64];
    __shared__ __align__(16) float f32BK[NSLOT][CK];   // 48B rows, 16B-aligned
    __shared__ double sA[258];

#define BARRIER() do {                                                  \
    __builtin_amdgcn_sched_barrier(0);                                  \
    asm volatile("" ::: "memory");                                      \
    __builtin_amdgcn_s_barrier();                                       \
    asm volatile("" ::: "memory");                                      \
    __builtin_amdgcn_sched_barrier(0);                                  \
} while (0)

#define WAIT_VM(n) do {                                                 \
    __builtin_amdgcn_sched_barrier(0);                                  \
    asm volatile("s_waitcnt vmcnt(" #n ")");                            \
    __builtin_amdgcn_sched_barrier(0);                                  \
} while (0)

    if (tid >= 64) {
        // ---------------- producer wave (r13-proven) ----------------
        // 25 VMEM per chunk: 1 blank (lanes 0..11 cover rows), 12+12 label rows.
#define ISSUE_CHUNK(k) do {                                             \
    const int slot_ = (k) & (NSLOT - 1);                                \
    {                                                                   \
        int tb_ = 1 + (k) * CK + L; if (tb_ > steps) tb_ = steps; if (tb_ < 0) tb_ = 0; \
        const float* g_ = base + (size_t)tb_ * Cc + blank;              \
        if (L < CK)                                                     \
            __builtin_amdgcn_global_load_lds(                           \
                (const __attribute__((address_space(1))) void*)g_,      \
                (__attribute__((address_space(3))) void*)&f32BK[slot_][0], 4, 0, 0); \
    }                                                                   \
    _Pragma("unroll")                                                   \
    for (int r_ = 0; r_ < CK; ++r_) {                                   \
        int t_ = 1 + (k) * CK + r_; if (t_ > steps) t_ = steps; if (t_ < 0) t_ = 0; \
        const float* row_ = base + (size_t)t_ * Cc;                     \
        __builtin_amdgcn_global_load_lds(                               \
            (const __attribute__((address_space(1))) void*)(row_ + lab1), \
            (__attribute__((address_space(3))) void*)&f32L1[slot_][r_][0], 4, 0, 0); \
        __builtin_amdgcn_global_load_lds(                               \
            (const __attribute__((address_space(1))) void*)(row_ + lab2), \
            (__attribute__((address_space(3))) void*)&f32L2[slot_][r_][0], 4, 0, 0); \
    }                                                                   \
} while (0)

        ISSUE_CHUNK(0);
        ISSUE_CHUNK(1);              // 50 outstanding
        WAIT_VM(25);                 // chunk 0 landed
        BARRIER();
        for (int i = 0; i < nch; ++i) {
            if (i + 2 < nch) {
                ISSUE_CHUNK(i + 2);  // <= 50 outstanding
                WAIT_VM(25);         // chunk i+1 landed (in-order)
            } else {
                WAIT_VM(0);          // tail: drain everything
            }
            BARRIER();
        }
        return;
#undef ISSUE_CHUNK
    }

    // ---------------- consumer wave (DP) ----------------
    const int  labp = (L > 0) ? yb[2 * L - 1] : -1;
    const double skm1 = ((L > 0) && (lab1 != blank) && (lab1 != labp)) ? 1.0 : 0.0;
    const double skm3 = ((lab2 != blank) && (lab2 != lab1)) ? 1.0 : 0.0;

    double a0 = 0.0, a1v = 0.0, a2v = 0.0, a3v = 0.0, a4v = 0.0;
    if (L == 0) {
        a0  = (double)(base[blank] + EPSf);
        a1v = (ll > 0) ? (double)(base[lab1] + EPSf) : 0.0;
    }
    int shift = 0;

#define DPSTEP(qb_, q1_, q2_) do {                                      \
    const double pa3_ = dpp_shr1_f64(a3v);                              \
    const double n0_ = (a0 + pa3_) * (qb_);                             \
    const double n1_ = fma(skm1, pa3_, a0 + a1v) * (q1_);               \
    const double n2_ = (a2v + a1v) * (qb_);                             \
    const double n3_ = fma(skm3, a1v, a3v + a2v) * (q2_);               \
    const double n4_ = (a4v + a3v) * (qb_);                             \
    a0 = n0_; a1v = n1_; a2v = n2_; a3v = n3_; a4v = n4_;               \
} while (0)

// Int-domain local max (alphas >= 0 -> hi-word int order == IEEE order),
// then DPP wave reduce; exact power-of-2 rescale.
#define RESCALE() do {                                                  \
    const int h0_ = __double2hiint(a0),  h1_ = __double2hiint(a1v);     \
    const int h2_ = __double2hiint(a2v), h3_ = __double2hiint(a3v);     \
    const int h4_ = __double2hiint(a4v);                                \
    int mh_ = h0_ > h1_ ? h0_ : h1_;                                    \
    mh_ = h2_ > mh_ ? h2_ : mh_;                                        \
    mh_ = h3_ > mh_ ? h3_ : mh_;                                        \
    mh_ = h4_ > mh_ ? h4_ : mh_;                                        \
    int be_ = (mh_ >> 20) & 0x7ff;                                      \
    be_ = dpp_max_i32(be_);                                             \
    const int emax_ = __builtin_amdgcn_readlane(be_, 63);               \
    const double sc_ = __hiloint2double((2046 - emax_) << 20, 0);       \
    a0 *= sc_; a1v *= sc_; a2v *= sc_; a3v *= sc_; a4v *= sc_;          \
    shift += emax_ - 1023;                                              \
} while (0)

    BARRIER();                       // matches producer prologue barrier

    for (int i = 0; i < nch; ++i) {
        const int slot = i & (NSLOT - 1);

        // Batch-read + convert the whole chunk into registers (static idx).
        // Blank: 12 floats = 3x float4 broadcast (ds_read_b128).
        double qb[CK], q1[CK], q2[CK];
        {
            const float4* bk4 = (const float4*)&f32BK[slot][0];
            const float4 v0 = bk4[0], v1 = bk4[1], v2 = bk4[2];
            qb[0]  = (double)(v0.x + EPSf); qb[1]  = (double)(v0.y + EPSf);
            qb[2]  = (double)(v0.z + EPSf); qb[3]  = (double)(v0.w + EPSf);
            qb[4]  = (double)(v1.x + EPSf); qb[5]  = (double)(v1.y + EPSf);
            qb[6]  = (double)(v1.z + EPSf); qb[7]  = (double)(v1.w + EPSf);
            qb[8]  = (double)(v2.x + EPSf); qb[9]  = (double)(v2.y + EPSf);
            qb[10] = (double)(v2.z + EPSf); qb[11] = (double)(v2.w + EPSf);
        }
#pragma unroll
        for (int r = 0; r < CK; ++r) {
            q1[r] = (double)(f32L1[slot][r][L] + EPSf);
            q2[r] = (double)(f32L2[slot][r][L] + EPSf);
        }

        if (i < nfull) {
#pragma unroll
            for (int r = 0; r < CK; ++r)
                DPSTEP(qb[r], q1[r], q2[r]);
        } else {
#pragma unroll
            for (int r = 0; r < CK; ++r) {
                if (1 + i * CK + r <= steps)
                    DPSTEP(qb[r], q1[r], q2[r]);
            }
        }
        if (i & 1) RESCALE();        // every 2 chunks (24 steps): exact pow-2;
                                     // decay bound 2^-798 >> 2^-1022 floor
        BARRIER();
    }

    // ---- readout (single wave; DS ops in-order within the wave) ----
    sA[4 * L + 0] = a0;
    sA[4 * L + 1] = a1v;
    sA[4 * L + 2] = a2v;
    sA[4 * L + 3] = a3v;
    if (L == 63) sA[256] = a4v;

    if (L == 0) {
        const int end = 2 * ll;
        const double ae = sA[end];
        int pi = end - 1; if (pi < 0) pi = 0;
        double ap = sA[pi];
        if (ll <= 0) ap = 0.0;
        const double s  = ae + ap;
        const double lg = log2(s) + (double)shift;
        out[b] = (float)(-0.6931471805599453 * lg);
    }

#undef BARRIER
#undef WAIT_VM
#undef DPSTEP
#undef RESCALE
}

extern "C" void kernel_launch(void* const* d_in, const int* in_sizes, int n_in,
                              void* d_out, int out_size, void* d_ws, size_t ws_size,
                              hipStream_t stream) {
    const int*   y_true  = (const int*)  d_in[0];
    const float* y_pred  = (const float*)d_in[1];
    const int*   in_len  = (const int*)  d_in[2];
    const int*   lab_len = (const int*)  d_in[3];
    float*       out     = (float*)      d_out;

    ctc_fwd_kernel<<<dim3(256), dim3(128), 0, stream>>>(y_true, y_pred, in_len, lab_len, out);
}

// Round 18
// 53.867 us; speedup vs baseline: 1.3162x; 1.0390x over previous
//
#include <hip/hip_runtime.h>

// CTC batch cost (keras ctc_batch_cost semantics), blank = C-1.
// 256 blocks x 128 threads: wave 0 = DP consumer, wave 1 = producer.
// Lane L owns states 4L..4L+3; lane 63 also owns state 256.
// f64 probability-domain DP, exact power-of-2 rescale every 2 chunks via
// int-domain exponent max + DPP reduce. Producer (r13/r17-proven,
// UNCHANGED): 25 global_load_lds per chunk into a 4-slot f32 LDS ring,
// depth-2 (50 outstanding), counted vmcnt(25) + raw s_barrier.
// NEW (r18): consumer software-pipelines the LDS read+convert of chunk
// i+1 (register set B) UNDER the DP of chunk i (set A) -- disjoint
// register sets, no fence between them, so the ~350cy read/cvt phase and
// the f64 dependency bubbles absorb each other. 2-chunk-unrolled loop
// keeps all register indexing static (named A/B sets, rule #20).
// Barrier count: 1 prologue + nch, matching the producer exactly.

constexpr int   Tn    = 1024;
constexpr int   Cc    = 128;
constexpr int   Ln    = 128;
constexpr float EPSf  = 1e-7f;
constexpr int   CK    = 12;    // rows per chunk; rescale every 2 chunks
constexpr int   NSLOT = 4;     // LDS ring slots

__device__ __forceinline__ int dpp_max_i32(int m) {
    int o;
    o = __builtin_amdgcn_update_dpp(0, m, 0x111, 0xf, 0xf, false); m = o > m ? o : m; // row_shr:1
    o = __builtin_amdgcn_update_dpp(0, m, 0x112, 0xf, 0xf, false); m = o > m ? o : m; // row_shr:2
    o = __builtin_amdgcn_update_dpp(0, m, 0x114, 0xf, 0xf, false); m = o > m ? o : m; // row_shr:4
    o = __builtin_amdgcn_update_dpp(0, m, 0x118, 0xf, 0xf, false); m = o > m ? o : m; // row_shr:8
    o = __builtin_amdgcn_update_dpp(0, m, 0x142, 0xf, 0xf, false); m = o > m ? o : m; // row_bcast:15
    o = __builtin_amdgcn_update_dpp(0, m, 0x143, 0xf, 0xf, false); m = o > m ? o : m; // row_bcast:31
    return m;   // lane 63 holds the wave max
}

// lane L gets lane L-1's value; lane 0 gets exact +0.0 (bound_ctrl=1).
__device__ __forceinline__ double dpp_shr1_f64(double x) {
    const int lo = __double2loint(x), hi = __double2hiint(x);
    const int slo = __builtin_amdgcn_update_dpp(0, lo, 0x138, 0xf, 0xf, true); // wave_shr:1
    const int shi = __builtin_amdgcn_update_dpp(0, hi, 0x138, 0xf, 0xf, true);
    return __hiloint2double(shi, slo);
}

__global__ __launch_bounds__(128, 1)
void ctc_fwd_kernel(const int*   __restrict__ y_true,
                    const float* __restrict__ y_pred,
                    const int*   __restrict__ in_len,
                    const int*   __restrict__ lab_len,
                    float*       __restrict__ out)
{
    const int tid = threadIdx.x;
    const int L   = tid & 63;            // lane within wave
    const int b   = blockIdx.x;
    const int il  = in_len[b];
    const int ll  = lab_len[b];
    const int blank = Cc - 1;

    const int* yb   = y_true + (size_t)b * Ln;
    const int  lab1 = yb[2 * L];                       // label for state 4L+1
    const int  lab2 = yb[2 * L + 1];                   // label for state 4L+3

    const float* base = y_pred + (size_t)b * Tn * Cc;
    const int steps = (il > 0) ? (il - 1) : 0;         // updates run t = 1 .. il-1
    const int nfull = steps / CK;
    const int nch   = (steps + CK - 1) / CK;

    __shared__ float f32L1[NSLOT][CK][64];
    __shared__ float f32L2[NSLOT][CK][64];
    __shared__ __align__(16) float f32BK[NSLOT][CK];   // 48B rows, 16B-aligned
    __shared__ double sA[258];

#define BARRIER() do {                                                  \
    __builtin_amdgcn_sched_barrier(0);                                  \
    asm volatile("" ::: "memory");                                      \
    __builtin_amdgcn_s_barrier();                                       \
    asm volatile("" ::: "memory");                                      \
    __builtin_amdgcn_sched_barrier(0);                                  \
} while (0)

#define WAIT_VM(n) do {                                                 \
    __builtin_amdgcn_sched_barrier(0);                                  \
    asm volatile("s_waitcnt vmcnt(" #n ")");                            \
    __builtin_amdgcn_sched_barrier(0);                                  \
} while (0)

    if (tid >= 64) {
        // ---------------- producer wave (r13/r17-proven, unchanged) ----------------
#define ISSUE_CHUNK(k) do {                                             \
    const int slot_ = (k) & (NSLOT - 1);                                \
    {                                                                   \
        int tb_ = 1 + (k) * CK + L; if (tb_ > steps) tb_ = steps; if (tb_ < 0) tb_ = 0; \
        const float* g_ = base + (size_t)tb_ * Cc + blank;              \
        if (L < CK)                                                     \
            __builtin_amdgcn_global_load_lds(                           \
                (const __attribute__((address_space(1))) void*)g_,      \
                (__attribute__((address_space(3))) void*)&f32BK[slot_][0], 4, 0, 0); \
    }                                                                   \
    _Pragma("unroll")                                                   \
    for (int r_ = 0; r_ < CK; ++r_) {                                   \
        int t_ = 1 + (k) * CK + r_; if (t_ > steps) t_ = steps; if (t_ < 0) t_ = 0; \
        const float* row_ = base + (size_t)t_ * Cc;                     \
        __builtin_amdgcn_global_load_lds(                               \
            (const __attribute__((address_space(1))) void*)(row_ + lab1), \
            (__attribute__((address_space(3))) void*)&f32L1[slot_][r_][0], 4, 0, 0); \
        __builtin_amdgcn_global_load_lds(                               \
            (const __attribute__((address_space(1))) void*)(row_ + lab2), \
            (__attribute__((address_space(3))) void*)&f32L2[slot_][r_][0], 4, 0, 0); \
    }                                                                   \
} while (0)

        ISSUE_CHUNK(0);
        ISSUE_CHUNK(1);              // 50 outstanding
        WAIT_VM(25);                 // chunk 0 landed
        BARRIER();
        for (int i = 0; i < nch; ++i) {
            if (i + 2 < nch) {
                ISSUE_CHUNK(i + 2);  // <= 50 outstanding
                WAIT_VM(25);         // chunk i+1 landed (in-order)
            } else {
                WAIT_VM(0);          // tail: drain everything
            }
            BARRIER();
        }
        return;
#undef ISSUE_CHUNK
    }

    // ---------------- consumer wave (DP, software-pipelined) ----------------
    const int  labp = (L > 0) ? yb[2 * L - 1] : -1;
    const double skm1 = ((L > 0) && (lab1 != blank) && (lab1 != labp)) ? 1.0 : 0.0;
    const double skm3 = ((lab2 != blank) && (lab2 != lab1)) ? 1.0 : 0.0;

    double a0 = 0.0, a1v = 0.0, a2v = 0.0, a3v = 0.0, a4v = 0.0;
    if (L == 0) {
        a0  = (double)(base[blank] + EPSf);
        a1v = (ll > 0) ? (double)(base[lab1] + EPSf) : 0.0;
    }
    int shift = 0;

    // Two named register sets (static indexing, rule #20).
    double qbA[CK], q1A[CK], q2A[CK];
    double qbB[CK], q1B[CK], q2B[CK];

#define READCVT(SET, k) do {                                            \
    const int slot_ = (k) & (NSLOT - 1);                                \
    {                                                                   \
        const float4* bk4_ = (const float4*)&f32BK[slot_][0];           \
        const float4 v0_ = bk4_[0], v1_ = bk4_[1], v2_ = bk4_[2];       \
        qb##SET[0]  = (double)(v0_.x + EPSf); qb##SET[1]  = (double)(v0_.y + EPSf); \
        qb##SET[2]  = (double)(v0_.z + EPSf); qb##SET[3]  = (double)(v0_.w + EPSf); \
        qb##SET[4]  = (double)(v1_.x + EPSf); qb##SET[5]  = (double)(v1_.y + EPSf); \
        qb##SET[6]  = (double)(v1_.z + EPSf); qb##SET[7]  = (double)(v1_.w + EPSf); \
        qb##SET[8]  = (double)(v2_.x + EPSf); qb##SET[9]  = (double)(v2_.y + EPSf); \
        qb##SET[10] = (double)(v2_.z + EPSf); qb##SET[11] = (double)(v2_.w + EPSf); \
    }                                                                   \
    _Pragma("unroll")                                                   \
    for (int r_ = 0; r_ < CK; ++r_) {                                   \
        q1##SET[r_] = (double)(f32L1[slot_][r_][L] + EPSf);             \
        q2##SET[r_] = (double)(f32L2[slot_][r_][L] + EPSf);             \
    }                                                                   \
} while (0)

#define DPSTEP(qb_, q1_, q2_) do {                                      \
    const double pa3_ = dpp_shr1_f64(a3v);                              \
    const double n0_ = (a0 + pa3_) * (qb_);                             \
    const double n1_ = fma(skm1, pa3_, a0 + a1v) * (q1_);               \
    const double n2_ = (a2v + a1v) * (qb_);                             \
    const double n3_ = fma(skm3, a1v, a3v + a2v) * (q2_);               \
    const double n4_ = (a4v + a3v) * (qb_);                             \
    a0 = n0_; a1v = n1_; a2v = n2_; a3v = n3_; a4v = n4_;               \
} while (0)

#define DPCHUNK_SET(SET, i_) do {                                       \
    if ((i_) < nfull) {                                                 \
        _Pragma("unroll")                                               \
        for (int r_ = 0; r_ < CK; ++r_)                                 \
            DPSTEP(qb##SET[r_], q1##SET[r_], q2##SET[r_]);              \
    } else {                                                            \
        _Pragma("unroll")                                               \
        for (int r_ = 0; r_ < CK; ++r_) {                               \
            if (1 + (i_) * CK + r_ <= steps)                            \
                DPSTEP(qb##SET[r_], q1##SET[r_], q2##SET[r_]);          \
        }                                                               \
    }                                                                   \
} while (0)

// Int-domain local max (alphas >= 0 -> hi-word int order == IEEE order),
// then DPP wave reduce; exact power-of-2 rescale.
#define RESCALE() do {                                                  \
    const int h0_ = __double2hiint(a0),  h1_ = __double2hiint(a1v);     \
    const int h2_ = __double2hiint(a2v), h3_ = __double2hiint(a3v);     \
    const int h4_ = __double2hiint(a4v);                                \
    int mh_ = h0_ > h1_ ? h0_ : h1_;                                    \
    mh_ = h2_ > mh_ ? h2_ : mh_;                                        \
    mh_ = h3_ > mh_ ? h3_ : mh_;                                        \
    mh_ = h4_ > mh_ ? h4_ : mh_;                                        \
    int be_ = (mh_ >> 20) & 0x7ff;                                      \
    be_ = dpp_max_i32(be_);                                             \
    const int emax_ = __builtin_amdgcn_readlane(be_, 63);               \
    const double sc_ = __hiloint2double((2046 - emax_) << 20, 0);       \
    a0 *= sc_; a1v *= sc_; a2v *= sc_; a3v *= sc_; a4v *= sc_;          \
    shift += emax_ - 1023;                                              \
} while (0)

    BARRIER();                       // #0: chunk 0 published
    READCVT(A, 0);                   // prime set A

    int i = 0;
    while (i + 2 <= nch) {
        BARRIER();                   // #(i+1): chunk i+1 published
        READCVT(B, i + 1);           // overlaps with DP of chunk i (set A)
        DPCHUNK_SET(A, i);

        BARRIER();                   // #(i+2): chunk i+2 published (or tail)
        if (i + 2 < nch) READCVT(A, i + 2);
        DPCHUNK_SET(B, i + 1);
        RESCALE();                   // every 2 chunks (24 steps): exact pow-2
        i += 2;
    }
    if (i < nch) {                   // odd leftover chunk (already in A)
        BARRIER();                   // #(i+1) = #nch (producer tail barrier)
        DPCHUNK_SET(A, i);
        // no rescale needed before readout (shift accounting is invariant)
    }

    // ---- readout (single wave; DS ops in-order within the wave) ----
    sA[4 * L + 0] = a0;
    sA[4 * L + 1] = a1v;
    sA[4 * L + 2] = a2v;
    sA[4 * L + 3] = a3v;
    if (L == 63) sA[256] = a4v;

    if (L == 0) {
        const int end = 2 * ll;
        const double ae = sA[end];
        int pi = end - 1; if (pi < 0) pi = 0;
        double ap = sA[pi];
        if (ll <= 0) ap = 0.0;
        const double s  = ae + ap;
        const double lg = log2(s) + (double)shift;
        out[b] = (float)(-0.6931471805599453 * lg);
    }

#undef BARRIER
#undef WAIT_VM
#undef READCVT
#undef DPSTEP
#undef DPCHUNK_SET
#undef RESCALE
}

extern "C" void kernel_launch(void* const* d_in, const int* in_sizes, int n_in,
                              void* d_out, int out_size, void* d_ws, size_t ws_size,
                              hipStream_t stream) {
    const int*   y_true  = (const int*)  d_in[0];
    const float* y_pred  = (const float*)d_in[1];
    const int*   in_len  = (const int*)  d_in[2];
    const int*   lab_len = (const int*)  d_in[3];
    float*       out     = (float*)      d_out;

    ctc_fwd_kernel<<<dim3(256), dim3(128), 0, stream>>>(y_true, y_pred, in_len, lab_len, out);
}